// Round 7
// baseline (272.126 us; speedup 1.0000x reference)
//
#include <hip/hip_runtime.h>
#include <math.h>

#define Bsz 2048
#define Ddim 32
#define Nsz 8192
#define Kk 30
#define TPB 256
#define ROWS 16                  // i-rows per block, staged in LDS (broadcast reads)
#define JSL 8                    // j-slices; each block covers TPB j's (one per thread)
#define JT (Bsz / JSL)           // 256 j per block == TPB
#define NBLK ((Bsz / ROWS) * JSL) // 128 * 8 = 1024 blocks = 4/CU = 16 waves/CU
#define NW (Nsz / 32)            // 256 bitset words per row

// R6 post-mortem: launch_bounds(512,4) drove the allocator to 64 VGPRs and the
// 200-value body spilled to scratch (FETCH 234MB, WRITE 233MB). R5's counters
// also showed main is HBM-bound on the POISON DRAIN: hbm_bytes 72MB (60MB of
// it dirty-fill writeback) at an effective 1.4TB/s = its entire 51us. The fix
// is not more VALU tuning -- it's miss-level parallelism with zero spill:
//   * one j-row per thread (32 VGPRs), ALL global loads issued in the first
//     ~100 cycles of the block (8 dwordx4 + samp + knn after one sync);
//   * no barriers and no global loads in the dot loop: 16 i-rows read from
//     LDS as lane-uniform BROADCAST (conflict-free), 4x the arithmetic
//     intensity of R5 (total z re-read 134MB -> 33MB of L2 traffic);
//   * register peak ~60-80 (mask packed to ONE uint; dval[16]+dot[16]+zj);
//   * 4 blocks/CU (16 waves/CU) via grid=1024, launch_bounds(256,4).
// Reduction: LDS-transpose reusing the dead 16KB bitset region; per-slice
// (den,num) partials; tiny final dispatch combines 8 slices + 2048 logs.
__global__ __launch_bounds__(TPB, 4) void softnp_main(
    const float* __restrict__ z,
    const int*   __restrict__ pre_knn,
    const int*   __restrict__ samp,
    float*       __restrict__ wsden,   // [JSL][Bsz] partial denominators
    float*       __restrict__ wsnum)   // [JSL][Bsz] partial masked numerators
{
    __shared__ unsigned bits[NW][ROWS];   // 16 KB; reused as reduce scratch later
    __shared__ float    zish[ROWS * Ddim];// 2 KB
    __shared__ float    sish[ROWS];
    __shared__ int      rowsi[ROWS];

    const int t  = threadIdx.x;
    const int g  = blockIdx.x >> 3;       // row-group (128 groups)
    const int s  = blockIdx.x & 7;        // j-slice: bid&7 ~ XCD -> slice/XCD locality
    const int i0 = g * ROWS;
    const int j  = s * JT + t;            // this thread's single j

    // ---- front-load ALL independent global traffic (MLP burst) ----
    float4 zj[8];
    const float4* zg = (const float4*)z;
    #pragma unroll
    for (int d = 0; d < 8; ++d) zj[d] = zg[(size_t)j * 8 + d];
    const int sj = samp[j];

    // stage: zero bitsets (4096 words / 256 thr), z_i rows, row ids
    #pragma unroll
    for (int c = 0; c < (NW * ROWS) / TPB; ++c)
        ((unsigned*)bits)[t + c * TPB] = 0u;
    zish[t]       = z[(size_t)i0 * Ddim + t];        // rows 0..7
    zish[t + TPB] = z[(size_t)i0 * Ddim + t + TPB];  // rows 8..15
    if (t < ROWS) rowsi[t] = samp[i0 + t];
    __syncthreads();

    // ---- fill bitsets: 16 rows x 30 entries = 480, 2 per thread ----
    #pragma unroll
    for (int c = 0; c < 2; ++c) {
        const int idx = t + c * TPB;
        if (idx < ROWS * Kk) {
            const int r  = idx / Kk, k = idx - r * Kk;
            const int id = pre_knn[(size_t)rowsi[r] * Kk + k];
            atomicOr(&bits[id >> 5][r], 1u << (id & 31));
        }
    }
    // |z_i|^2 for the 16 rows (t<16), reads zish staged above
    if (t < ROWS) {
        float a = 0.f;
        #pragma unroll
        for (int d = 0; d < Ddim; ++d) {
            const float w = zish[t * Ddim + d];
            a += w * w;
        }
        sish[t] = a;
    }
    __syncthreads();   // bits + sish ready

    // ---- dot loop: pure LDS-broadcast + FMA, no barriers, no global ----
    float dot[ROWS];
    #pragma unroll
    for (int r = 0; r < ROWS; ++r) dot[r] = 0.f;
    float sj2 = 0.f;
    const float4* z4s = (const float4*)zish;
    #pragma unroll
    for (int d = 0; d < 8; ++d) {
        const float4 v = zj[d];
        sj2 += v.x * v.x + v.y * v.y + v.z * v.z + v.w * v.w;
        #pragma unroll
        for (int r = 0; r < ROWS; ++r) {
            const float4 w = z4s[r * 8 + d];     // lane-uniform broadcast read
            dot[r] += w.x * v.x + w.y * v.y + w.z * v.z + w.w * v.w;
        }
    }

    // ---- mask bits for this j across 16 rows -> ONE packed register ----
    const int wword = sj >> 5, wbit = sj & 31;
    const uint4* b4 = (const uint4*)bits;
    const uint4 q0 = b4[wword * 4 + 0], q1 = b4[wword * 4 + 1];
    const uint4 q2 = b4[wword * 4 + 2], q3 = b4[wword * 4 + 3];
    const unsigned bsel[ROWS] = {q0.x, q0.y, q0.z, q0.w, q1.x, q1.y, q1.z, q1.w,
                                 q2.x, q2.y, q2.z, q2.w, q3.x, q3.y, q3.z, q3.w};
    unsigned nmask = 0u;
    const int dr = j - i0;               // diag <=> r == dr
    float dval[ROWS];
    #pragma unroll
    for (int r = 0; r < ROWS; ++r) {
        const float d2 = fmaxf(sish[r] + sj2 - 2.f * dot[r], 0.f);
        const bool diag = (r == dr);
        const float e = diag ? 0.f : __expf(-sqrtf(d2));
        dval[r] = e;
        if (!diag && ((bsel[r] >> wbit) & 1u)) nmask |= 1u << r;
    }

    // ---- reduce 256 threads -> 16 row sums, via LDS transpose ----
    // (reuse the dead 16 KB bitset region; rotation avoids bank conflicts)
    __syncthreads();                     // all bits reads complete
    float* sc = (float*)bits;            // [ROWS][TPB] = 4096 floats
    const int gsel = t >> 4, m = t & 15; // 16 groups x 16 lanes; group = row

    #pragma unroll
    for (int r = 0; r < ROWS; ++r) sc[r * TPB + t] = dval[r];
    __syncthreads();
    float a = 0.f;
    #pragma unroll
    for (int k = 0; k < 16; ++k)
        a += sc[gsel * TPB + m * 16 + ((k + m) & 15)];
    a += __shfl_xor(a, 1, 64); a += __shfl_xor(a, 2, 64);
    a += __shfl_xor(a, 4, 64); a += __shfl_xor(a, 8, 64);
    if (m == 0) wsden[s * Bsz + i0 + gsel] = a;   // pure overwrite

    __syncthreads();
    #pragma unroll
    for (int r = 0; r < ROWS; ++r)
        sc[r * TPB + t] = ((nmask >> r) & 1u) ? dval[r] : 0.f;
    __syncthreads();
    float b = 0.f;
    #pragma unroll
    for (int k = 0; k < 16; ++k)
        b += sc[gsel * TPB + m * 16 + ((k + m) & 15)];
    b += __shfl_xor(b, 1, 64); b += __shfl_xor(b, 2, 64);
    b += __shfl_xor(b, 4, 64); b += __shfl_xor(b, 8, 64);
    if (m == 0) wsnum[s * Bsz + i0 + gsel] = b;   // pure overwrite
}

// Tail: combine 8 slice-partials per row, 2048 logs, one scalar. ~128 KB read.
__global__ __launch_bounds__(TPB) void softnp_final(
    const float* __restrict__ wsden,
    const float* __restrict__ wsnum,
    float*       __restrict__ out)
{
    __shared__ float rl[4], rc[4];
    const int t = threadIdx.x;
    float loss = 0.f, vcnt = 0.f;
    #pragma unroll
    for (int c = 0; c < Bsz / TPB; ++c) {
        const int i = t + c * TPB;
        float D = 0.f, N = 0.f;
        #pragma unroll
        for (int sl = 0; sl < JSL; ++sl) {
            D += wsden[sl * Bsz + i];
            N += wsnum[sl * Bsz + i];
        }
        if (N > 0.f) {            // valid <=> any masked neighbor (no underflow:
            loss -= __logf(N / D + 1e-8f);   // exp(-d) >= ~e^-16 for this data)
            vcnt += 1.f;
        }
    }
    #pragma unroll
    for (int off = 32; off > 0; off >>= 1) {
        loss += __shfl_xor(loss, off, 64);
        vcnt += __shfl_xor(vcnt, off, 64);
    }
    const int lane = t & 63, wv = t >> 6;
    if (lane == 0) { rl[wv] = loss; rc[wv] = vcnt; }
    __syncthreads();
    if (t == 0) {
        const float L = rl[0] + rl[1] + rl[2] + rl[3];
        const float C = rc[0] + rc[1] + rc[2] + rc[3];
        out[0] = (C > 0.f) ? L / C : 0.f;
    }
}

extern "C" void kernel_launch(void* const* d_in, const int* in_sizes, int n_in,
                              void* d_out, int out_size, void* d_ws, size_t ws_size,
                              hipStream_t stream)
{
    const float* z       = (const float*)d_in[0];
    const int*   pre_knn = (const int*)d_in[1];
    const int*   samp    = (const int*)d_in[2];
    float*       out     = (float*)d_out;
    float*       wsden   = (float*)d_ws;             // [JSL][Bsz]
    float*       wsnum   = wsden + JSL * Bsz;        // [JSL][Bsz]

    // No memset: every (slice,row) ws slot is overwritten by softnp_main.
    softnp_main<<<dim3(NBLK), dim3(TPB), 0, stream>>>(z, pre_knn, samp, wsden, wsnum);
    softnp_final<<<dim3(1), dim3(TPB), 0, stream>>>(wsden, wsnum, out);
}

// Round 8
// 171.068 us; speedup vs baseline: 1.5907x; 1.5907x over previous
//
#include <hip/hip_runtime.h>
#include <math.h>

#define Bsz 2048
#define Ddim 32
#define Nsz 8192
#define Kk 30
#define TPB 256
#define ROWS 16                  // i-rows per block, staged in LDS (broadcast reads)
#define JSL 8                    // j-slices; each block covers TPB j's (one per thread)
#define JT (Bsz / JSL)           // 256 j per block == TPB
#define NBLK ((Bsz / ROWS) * JSL) // 128 * 8 = 1024 blocks -> 4/CU at <=128 VGPR
#define NW (Nsz / 32)            // 256 bitset words per row

// R6+R7 established an empirical law: __launch_bounds__(.,4) forces the
// allocator to 64 VGPRs and this ~100-live-value body spills ~650MB to
// scratch (R7: FETCH 219MB WRITE 432MB, 212us). __launch_bounds__(.,2)
// lands at 128 VGPRs with ZERO spill (R5: FETCH 9.7MB). So: keep R7's
// validated structure -- one j per thread, all global traffic front-loaded
// (max MLP), no barriers/loads in the dot loop, 16-row amortization (z
// re-read only ~34MB of L2 traffic; z itself is just 256KB) -- and take
// occupancy from the GRID: 1024 blocks at ~128 VGPR + 19KB LDS = 4
// blocks/CU = 16 waves/CU, fully resident in one round. bounds arg stays 2.
__global__ __launch_bounds__(TPB, 2) void softnp_main(
    const float* __restrict__ z,
    const int*   __restrict__ pre_knn,
    const int*   __restrict__ samp,
    float*       __restrict__ wsden,   // [JSL][Bsz] partial denominators
    float*       __restrict__ wsnum)   // [JSL][Bsz] partial masked numerators
{
    __shared__ unsigned bits[NW][ROWS];   // 16 KB; reused as reduce scratch later
    __shared__ float    zish[ROWS * Ddim];// 2 KB
    __shared__ float    sish[ROWS];
    __shared__ int      rowsi[ROWS];

    const int t  = threadIdx.x;
    const int g  = blockIdx.x >> 3;       // row-group (128 groups)
    const int s  = blockIdx.x & 7;        // j-slice: bid&7 ~ XCD -> slice/XCD locality
    const int i0 = g * ROWS;
    const int j  = s * JT + t;            // this thread's single j

    // ---- front-load ALL independent global traffic (MLP burst) ----
    float4 zj[8];
    const float4* zg = (const float4*)z;
    #pragma unroll
    for (int d = 0; d < 8; ++d) zj[d] = zg[(size_t)j * 8 + d];
    const int sj = samp[j];

    // stage: zero bitsets (4096 words / 256 thr), z_i rows, row ids
    #pragma unroll
    for (int c = 0; c < (NW * ROWS) / TPB; ++c)
        ((unsigned*)bits)[t + c * TPB] = 0u;
    zish[t]       = z[(size_t)i0 * Ddim + t];        // rows 0..7
    zish[t + TPB] = z[(size_t)i0 * Ddim + t + TPB];  // rows 8..15
    if (t < ROWS) rowsi[t] = samp[i0 + t];
    __syncthreads();

    // ---- fill bitsets: 16 rows x 30 entries = 480, 2 per thread ----
    #pragma unroll
    for (int c = 0; c < 2; ++c) {
        const int idx = t + c * TPB;
        if (idx < ROWS * Kk) {
            const int r  = idx / Kk, k = idx - r * Kk;
            const int id = pre_knn[(size_t)rowsi[r] * Kk + k];
            atomicOr(&bits[id >> 5][r], 1u << (id & 31));
        }
    }
    // |z_i|^2 for the 16 rows (t<16), reads zish staged above
    if (t < ROWS) {
        float a = 0.f;
        #pragma unroll
        for (int d = 0; d < Ddim; ++d) {
            const float w = zish[t * Ddim + d];
            a += w * w;
        }
        sish[t] = a;
    }
    __syncthreads();   // bits + sish ready

    // ---- dot loop: pure LDS-broadcast + FMA, no barriers, no global ----
    float dot[ROWS];
    #pragma unroll
    for (int r = 0; r < ROWS; ++r) dot[r] = 0.f;
    float sj2 = 0.f;
    const float4* z4s = (const float4*)zish;
    #pragma unroll
    for (int d = 0; d < 8; ++d) {
        const float4 v = zj[d];
        sj2 += v.x * v.x + v.y * v.y + v.z * v.z + v.w * v.w;
        #pragma unroll
        for (int r = 0; r < ROWS; ++r) {
            const float4 w = z4s[r * 8 + d];     // lane-uniform broadcast read
            dot[r] += w.x * v.x + w.y * v.y + w.z * v.z + w.w * v.w;
        }
    }

    // ---- mask bits for this j across 16 rows -> ONE packed register ----
    const int wword = sj >> 5, wbit = sj & 31;
    const uint4* b4 = (const uint4*)bits;
    const uint4 q0 = b4[wword * 4 + 0], q1 = b4[wword * 4 + 1];
    const uint4 q2 = b4[wword * 4 + 2], q3 = b4[wword * 4 + 3];
    const unsigned bsel[ROWS] = {q0.x, q0.y, q0.z, q0.w, q1.x, q1.y, q1.z, q1.w,
                                 q2.x, q2.y, q2.z, q2.w, q3.x, q3.y, q3.z, q3.w};
    unsigned nmask = 0u;
    const int dr = j - i0;               // diag <=> r == dr
    float dval[ROWS];
    #pragma unroll
    for (int r = 0; r < ROWS; ++r) {
        const float d2 = fmaxf(sish[r] + sj2 - 2.f * dot[r], 0.f);
        const bool diag = (r == dr);
        const float e = diag ? 0.f : __expf(-sqrtf(d2));
        dval[r] = e;
        if (!diag && ((bsel[r] >> wbit) & 1u)) nmask |= 1u << r;
    }

    // ---- reduce 256 threads -> 16 row sums, via LDS transpose ----
    // (reuse the dead 16 KB bitset region; rotation avoids bank conflicts)
    __syncthreads();                     // all bits reads complete
    float* sc = (float*)bits;            // [ROWS][TPB] = 4096 floats
    const int gsel = t >> 4, m = t & 15; // 16 groups x 16 lanes; group = row

    #pragma unroll
    for (int r = 0; r < ROWS; ++r) sc[r * TPB + t] = dval[r];
    __syncthreads();
    float a = 0.f;
    #pragma unroll
    for (int k = 0; k < 16; ++k)
        a += sc[gsel * TPB + m * 16 + ((k + m) & 15)];
    a += __shfl_xor(a, 1, 64); a += __shfl_xor(a, 2, 64);
    a += __shfl_xor(a, 4, 64); a += __shfl_xor(a, 8, 64);
    if (m == 0) wsden[s * Bsz + i0 + gsel] = a;   // pure overwrite

    __syncthreads();
    #pragma unroll
    for (int r = 0; r < ROWS; ++r)
        sc[r * TPB + t] = ((nmask >> r) & 1u) ? dval[r] : 0.f;
    __syncthreads();
    float b = 0.f;
    #pragma unroll
    for (int k = 0; k < 16; ++k)
        b += sc[gsel * TPB + m * 16 + ((k + m) & 15)];
    b += __shfl_xor(b, 1, 64); b += __shfl_xor(b, 2, 64);
    b += __shfl_xor(b, 4, 64); b += __shfl_xor(b, 8, 64);
    if (m == 0) wsnum[s * Bsz + i0 + gsel] = b;   // pure overwrite
}

// Tail: combine 8 slice-partials per row, 2048 logs, one scalar. ~128 KB read.
__global__ __launch_bounds__(TPB) void softnp_final(
    const float* __restrict__ wsden,
    const float* __restrict__ wsnum,
    float*       __restrict__ out)
{
    __shared__ float rl[4], rc[4];
    const int t = threadIdx.x;
    float loss = 0.f, vcnt = 0.f;
    #pragma unroll
    for (int c = 0; c < Bsz / TPB; ++c) {
        const int i = t + c * TPB;
        float D = 0.f, N = 0.f;
        #pragma unroll
        for (int sl = 0; sl < JSL; ++sl) {
            D += wsden[sl * Bsz + i];
            N += wsnum[sl * Bsz + i];
        }
        if (N > 0.f) {            // valid <=> any masked neighbor (no underflow:
            loss -= __logf(N / D + 1e-8f);   // exp(-d) >= ~e^-16 for this data)
            vcnt += 1.f;
        }
    }
    #pragma unroll
    for (int off = 32; off > 0; off >>= 1) {
        loss += __shfl_xor(loss, off, 64);
        vcnt += __shfl_xor(vcnt, off, 64);
    }
    const int lane = t & 63, wv = t >> 6;
    if (lane == 0) { rl[wv] = loss; rc[wv] = vcnt; }
    __syncthreads();
    if (t == 0) {
        const float L = rl[0] + rl[1] + rl[2] + rl[3];
        const float C = rc[0] + rc[1] + rc[2] + rc[3];
        out[0] = (C > 0.f) ? L / C : 0.f;
    }
}

extern "C" void kernel_launch(void* const* d_in, const int* in_sizes, int n_in,
                              void* d_out, int out_size, void* d_ws, size_t ws_size,
                              hipStream_t stream)
{
    const float* z       = (const float*)d_in[0];
    const int*   pre_knn = (const int*)d_in[1];
    const int*   samp    = (const int*)d_in[2];
    float*       out     = (float*)d_out;
    float*       wsden   = (float*)d_ws;             // [JSL][Bsz]
    float*       wsnum   = wsden + JSL * Bsz;        // [JSL][Bsz]

    // No memset: every (slice,row) ws slot is overwritten by softnp_main.
    softnp_main<<<dim3(NBLK), dim3(TPB), 0, stream>>>(z, pre_knn, samp, wsden, wsnum);
    softnp_final<<<dim3(1), dim3(TPB), 0, stream>>>(wsden, wsnum, out);
}